// Round 9
// baseline (173.983 us; speedup 1.0000x reference)
//
#include <hip/hip_runtime.h>
#include <math.h>

// Problem constants (from reference): DM=512, DS=16, K=4, EXPAND=1
#define DMc   512
#define DIc   512
#define DSc   16
#define KCc   4
#define DTRc  32          // (512+15)//16
#define NXDc  64          // DTR + 2*DS
#define LLEN  2048
#define BBc   4
#define BLT   (BBc*LLEN)  // 8192

// chunked scan config
#define NCH   128         // chunks per sequence
#define CLEN  (LLEN/NCH)  // 16

typedef __attribute__((ext_vector_type(8))) short short8;
typedef __attribute__((ext_vector_type(8))) unsigned short ushort8;
typedef __attribute__((ext_vector_type(4))) unsigned short bf16x4_t;
typedef __attribute__((ext_vector_type(4))) float f32x4;

__device__ __forceinline__ float sigmoidf_(float x) { return 1.f / (1.f + __expf(-x)); }

// round-to-nearest-even f32 -> bf16 bits
__device__ __forceinline__ unsigned short f2bf(float x) {
    unsigned int u = __float_as_uint(x);
    u = (u + 0x7FFFu + ((u >> 16) & 1u)) >> 16;
    return (unsigned short)u;
}
__device__ __forceinline__ float bf2f(unsigned short u) {
    return __uint_as_float((unsigned int)u << 16);
}

// ---------------------------------------------------------------------------
// fused f32 -> bf16 conversion of x, W_in, W_out (one launch, 8 elems/thread)
// ---------------------------------------------------------------------------
#define CN1 (BLT * DMc / 8)        // x
#define CN2 (1024 * DMc / 8)       // W_in
#define CN3 (DMc * DIc / 8)        // W_out
__global__ __launch_bounds__(256) void convert3_kernel(const float* __restrict__ x,
                                                       const float* __restrict__ Win,
                                                       const float* __restrict__ Wout,
                                                       unsigned short* __restrict__ xb,
                                                       unsigned short* __restrict__ Wb,
                                                       unsigned short* __restrict__ Wob)
{
    int i = blockIdx.x * 256 + threadIdx.x;
    const float* src; unsigned short* dst;
    if (i < CN1)                  { src = x;    dst = xb;  }
    else if (i < CN1 + CN2)       { src = Win;  dst = Wb;  i -= CN1; }
    else if (i < CN1 + CN2 + CN3) { src = Wout; dst = Wob; i -= CN1 + CN2; }
    else return;
    float4 a = ((const float4*)src)[2 * i];
    float4 b = ((const float4*)src)[2 * i + 1];
    ushort8 o;
    o[0] = f2bf(a.x); o[1] = f2bf(a.y); o[2] = f2bf(a.z); o[3] = f2bf(a.w);
    o[4] = f2bf(b.x); o[5] = f2bf(b.y); o[6] = f2bf(b.z); o[7] = f2bf(b.w);
    ((ushort8*)dst)[i] = o;
}

// ---------------------------------------------------------------------------
// f32 tiled GEMM: C[M,N] = A[M,K] * B[N,K]^T, strides lda/ldb/ldc.
// 64x64 tile, BK=16, 256 threads, 4x4 micro-tile per thread.
// EPI==2: v = softplus(v + bias[col]) (dt projection).
// ---------------------------------------------------------------------------
template<int EPI>
__global__ __launch_bounds__(256) void gemm_bt_f32(const float* __restrict__ A,
                                                   const float* __restrict__ Bw,
                                                   const float* __restrict__ bias,
                                                   float* __restrict__ C,
                                                   int M, int N, int Kd,
                                                   int lda, int ldb, int ldc)
{
    __shared__ float As[16][68];
    __shared__ float Bs[16][68];
    const int tid  = threadIdx.x;
    const int tx   = tid & 15;
    const int ty   = tid >> 4;
    const int arow = tid >> 2;
    const int akq  = (tid & 3) << 2;

    const float* Ab = A  + (size_t)(blockIdx.y * 64 + arow) * lda + akq;
    const float* Bb = Bw + (size_t)(blockIdx.x * 64 + arow) * ldb + akq;

    float acc[4][4] = {};

    for (int k0 = 0; k0 < Kd; k0 += 16) {
        float4 av = *(const float4*)(Ab + k0);
        float4 bv = *(const float4*)(Bb + k0);
        __syncthreads();
        As[akq + 0][arow] = av.x; As[akq + 1][arow] = av.y;
        As[akq + 2][arow] = av.z; As[akq + 3][arow] = av.w;
        Bs[akq + 0][arow] = bv.x; Bs[akq + 1][arow] = bv.y;
        Bs[akq + 2][arow] = bv.z; Bs[akq + 3][arow] = bv.w;
        __syncthreads();
#pragma unroll
        for (int k = 0; k < 16; ++k) {
            float4 a = *(const float4*)&As[k][ty << 2];
            float4 b = *(const float4*)&Bs[k][tx << 2];
            float ar[4] = {a.x, a.y, a.z, a.w};
            float br[4] = {b.x, b.y, b.z, b.w};
#pragma unroll
            for (int i = 0; i < 4; ++i)
#pragma unroll
                for (int j = 0; j < 4; ++j)
                    acc[i][j] += ar[i] * br[j];
        }
    }

    float4 bv = make_float4(0.f, 0.f, 0.f, 0.f);
    if (EPI == 2) bv = *(const float4*)(bias + blockIdx.x * 64 + (tx << 2));
#pragma unroll
    for (int i = 0; i < 4; ++i) {
        float v[4] = {acc[i][0], acc[i][1], acc[i][2], acc[i][3]};
        if (EPI == 2) {
            float bb[4] = {bv.x, bv.y, bv.z, bv.w};
#pragma unroll
            for (int j = 0; j < 4; ++j) {
                float s = v[j] + bb[j];
                v[j] = fmaxf(s, 0.f) + log1pf(__expf(-fabsf(s)));
            }
        }
        *(float4*)(C + (size_t)(blockIdx.y * 64 + (ty << 2) + i) * ldc
                     + blockIdx.x * 64 + (tx << 2)) = make_float4(v[0], v[1], v[2], v[3]);
    }
}

// ---------------------------------------------------------------------------
// x_dbl projection GEMM: C[M,64] = A_bf16[M,512] * B_f32[64,512]^T.
// Same 64x64/BK=16 structure; A converted bf16->f32 during LDS staging.
// ---------------------------------------------------------------------------
__global__ __launch_bounds__(256) void gemm_xdbl(const unsigned short* __restrict__ A,
                                                 const float* __restrict__ Bw,
                                                 float* __restrict__ C)
{
    __shared__ float As[16][68];
    __shared__ float Bs[16][68];
    const int tid  = threadIdx.x;
    const int tx   = tid & 15;
    const int ty   = tid >> 4;
    const int arow = tid >> 2;
    const int akq  = (tid & 3) << 2;

    const unsigned short* Ab = A + (size_t)(blockIdx.y * 64 + arow) * DIc + akq;
    const float*          Bb = Bw + (size_t)arow * DIc + akq;

    float acc[4][4] = {};

    for (int k0 = 0; k0 < DIc; k0 += 16) {
        bf16x4_t av = *(const bf16x4_t*)(Ab + k0);
        float4   bv = *(const float4*)(Bb + k0);
        __syncthreads();
        As[akq + 0][arow] = bf2f(av[0]); As[akq + 1][arow] = bf2f(av[1]);
        As[akq + 2][arow] = bf2f(av[2]); As[akq + 3][arow] = bf2f(av[3]);
        Bs[akq + 0][arow] = bv.x; Bs[akq + 1][arow] = bv.y;
        Bs[akq + 2][arow] = bv.z; Bs[akq + 3][arow] = bv.w;
        __syncthreads();
#pragma unroll
        for (int k = 0; k < 16; ++k) {
            float4 a = *(const float4*)&As[k][ty << 2];
            float4 b = *(const float4*)&Bs[k][tx << 2];
            float ar[4] = {a.x, a.y, a.z, a.w};
            float br[4] = {b.x, b.y, b.z, b.w};
#pragma unroll
            for (int i = 0; i < 4; ++i)
#pragma unroll
                for (int j = 0; j < 4; ++j)
                    acc[i][j] += ar[i] * br[j];
        }
    }

#pragma unroll
    for (int i = 0; i < 4; ++i)
        *(float4*)(C + (size_t)(blockIdx.y * 64 + (ty << 2) + i) * NXDc + (tx << 2))
            = make_float4(acc[i][0], acc[i][1], acc[i][2], acc[i][3]);
}

// ---------------------------------------------------------------------------
// bf16 MFMA GEMM: C[M,N] = A[M,K] * B[N,K]^T, f32 accumulate.
// 128x128 tile, BK=32, 4 waves. XCD-aware bijective block swizzle (T1):
// requires nwg % 8 == 0 (true for both launches). OBF==1: bf16 output.
// EPI==1: clip to [-1000,1000], NaN->0 (f32 output path).
// ---------------------------------------------------------------------------
template<int EPI, int OBF>
__global__ __launch_bounds__(256) void gemm_mfma(const unsigned short* __restrict__ A,
                                                 const unsigned short* __restrict__ Bw,
                                                 float* __restrict__ Cf,
                                                 unsigned short* __restrict__ Cb,
                                                 int N, int Kd)
{
    // XCD swizzle: hw id -> logical so blocks sharing the A-panel co-reside per XCD
    const int nwg  = gridDim.x * gridDim.y;
    const int orig = blockIdx.y * gridDim.x + blockIdx.x;
    const int lg   = (orig & 7) * (nwg >> 3) + (orig >> 3);
    const int bx   = lg % gridDim.x;
    const int by   = lg / gridDim.x;

    __shared__ short As[128][40];
    __shared__ short Bs[128][40];
    const int tid  = threadIdx.x;
    const int lane = tid & 63;
    const int wv   = tid >> 6;
    const int wr   = wv >> 1;
    const int wc   = wv & 1;
    const int fr   = lane & 15;
    const int fq   = lane >> 4;

    const int rowA0 = by * 128;
    const int rowB0 = bx * 128;

    const int r0 = tid >> 2,        s0 = (tid & 3) << 3;
    const int r1 = (tid + 256) >> 2, s1 = s0;

    f32x4 acc[4][4];
#pragma unroll
    for (int m = 0; m < 4; ++m)
#pragma unroll
        for (int n = 0; n < 4; ++n) acc[m][n] = (f32x4){0.f, 0.f, 0.f, 0.f};

    for (int k0 = 0; k0 < Kd; k0 += 32) {
        short8 a0 = *(const short8*)(A  + (size_t)(rowA0 + r0) * Kd + k0 + s0);
        short8 a1 = *(const short8*)(A  + (size_t)(rowA0 + r1) * Kd + k0 + s1);
        short8 b0 = *(const short8*)(Bw + (size_t)(rowB0 + r0) * Kd + k0 + s0);
        short8 b1 = *(const short8*)(Bw + (size_t)(rowB0 + r1) * Kd + k0 + s1);
        __syncthreads();
        *(short8*)&As[r0][s0] = a0;
        *(short8*)&As[r1][s1] = a1;
        *(short8*)&Bs[r0][s0] = b0;
        *(short8*)&Bs[r1][s1] = b1;
        __syncthreads();

        short8 af[4], bf[4];
#pragma unroll
        for (int m = 0; m < 4; ++m)
            af[m] = *(const short8*)&As[wr * 64 + m * 16 + fr][fq << 3];
#pragma unroll
        for (int n = 0; n < 4; ++n)
            bf[n] = *(const short8*)&Bs[wc * 64 + n * 16 + fr][fq << 3];
#pragma unroll
        for (int m = 0; m < 4; ++m)
#pragma unroll
            for (int n = 0; n < 4; ++n)
                acc[m][n] = __builtin_amdgcn_mfma_f32_16x16x32_bf16(af[m], bf[n], acc[m][n], 0, 0, 0);
    }

    const int crow0 = rowA0 + wr * 64 + (fq << 2);
    const int ccol0 = rowB0 + wc * 64 + fr;
#pragma unroll
    for (int m = 0; m < 4; ++m)
#pragma unroll
        for (int n = 0; n < 4; ++n)
#pragma unroll
            for (int j = 0; j < 4; ++j) {
                float v = acc[m][n][j];
                if (EPI) v = (v != v) ? 0.f : fminf(fmaxf(v, -1000.f), 1000.f);
                size_t off = (size_t)(crow0 + m * 16 + j) * N + ccol0 + n * 16;
                if (OBF) Cb[off] = f2bf(v);
                else     Cf[off] = v;
            }
}

// ---------------------------------------------------------------------------
// Depthwise causal conv (K=4) + bias + SiLU, bf16 in (x-half of xzb), bf16 out.
// 8 channels per thread (vectorized ushort8 loads/stores).
// ---------------------------------------------------------------------------
__global__ __launch_bounds__(256) void conv_silu_kernel(const unsigned short* __restrict__ xzb,
                                                        const float* __restrict__ cw,
                                                        const float* __restrict__ cb,
                                                        unsigned short* __restrict__ xcb)
{
    int gid = blockIdx.x * 256 + threadIdx.x;   // over BLT*DIc/8 = 2^19
    int d8 = gid & 63;
    int l  = (gid >> 6) & (LLEN - 1);
    int b  = gid >> 17;
    int d0 = d8 << 3;

    float s[8];
#pragma unroll
    for (int j = 0; j < 8; ++j) s[j] = cb[d0 + j];
#pragma unroll
    for (int k = 0; k < KCc; ++k) {
        int ls = l + k - (KCc - 1);
        if (ls >= 0) {
            ushort8 v = *(const ushort8*)(xzb + (((size_t)(b * LLEN + ls)) << 10) + d0);
#pragma unroll
            for (int j = 0; j < 8; ++j)
                s[j] += bf2f(v[j]) * cw[(d0 + j) * KCc + k];
        }
    }
    ushort8 o;
#pragma unroll
    for (int j = 0; j < 8; ++j) {
        float v = s[j] * sigmoidf_(s[j]);
        o[j] = f2bf(v);
    }
    *(ushort8*)(xcb + ((size_t)gid << 3)) = o;
}

// ---------------------------------------------------------------------------
// Chunked parallel scan. dt (f32) in dtz[row*512+d]; z bf16 in xzb cols 512+;
// xc bf16 in xcb. hstate[b,c,s,d]: h_end after phase1, h_in after phase2.
// ---------------------------------------------------------------------------
__device__ __forceinline__ size_t hs_off(int b, int c, int s, int d) {
    return ((size_t)((b * NCH + c) * DSc + s) << 9) + d;
}

__global__ __launch_bounds__(256) void scan_phase1(const float* __restrict__ dtz,
                                                   const unsigned short* __restrict__ xcb,
                                                   const float* __restrict__ xdbl,
                                                   const float* __restrict__ A_log,
                                                   float* __restrict__ hstate,
                                                   float* __restrict__ sdtbuf)
{
    int half = blockIdx.x & 1;
    int c    = (blockIdx.x >> 1) & (NCH - 1);
    int b    = blockIdx.x >> 8;
    int d    = (half << 8) + threadIdx.x;
    int row0 = b * LLEN + c * CLEN;

    __shared__ float bc[CLEN][32];   // [t][0:16]=B
    {
        int r = threadIdx.x >> 4, col = (threadIdx.x & 15) << 1;
        const float* src = xdbl + (size_t)(row0 + r) * NXDc + DTRc + col;
        bc[r][col] = src[0]; bc[r][col + 1] = src[1];
    }

    float A[DSc];
#pragma unroll
    for (int s = 0; s < DSc; ++s) A[s] = -__expf(A_log[d * DSc + s]);

    float dtv[CLEN], xcv[CLEN];
#pragma unroll
    for (int t = 0; t < CLEN; ++t) {
        dtv[t] = dtz[((size_t)(row0 + t) << 9) + d];
        xcv[t] = bf2f(xcb[((size_t)(row0 + t) << 9) + d]);
    }
    __syncthreads();

    float h[DSc] = {};
    float Sdt = 0.f;
#pragma unroll
    for (int t = 0; t < CLEN; ++t) {
        float dBx = dtv[t] * xcv[t];
        Sdt += dtv[t];
#pragma unroll
        for (int s = 0; s < DSc; ++s)
            h[s] = __expf(dtv[t] * A[s]) * h[s] + dBx * bc[t][s];
    }
#pragma unroll
    for (int s = 0; s < DSc; ++s) hstate[hs_off(b, c, s, d)] = h[s];
    sdtbuf[((size_t)(b * NCH + c) << 9) + d] = Sdt;
}

__global__ __launch_bounds__(64) void scan_phase2(float* __restrict__ hstate,
                                                  const float* __restrict__ sdtbuf,
                                                  const float* __restrict__ A_log)
{
    int gid = blockIdx.x * 64 + threadIdx.x;    // over B*DSc*DIc = 32768
    int d = gid & (DIc - 1);
    int s = (gid >> 9) & (DSc - 1);
    int b = gid >> 13;

    float A = -__expf(A_log[d * DSc + s]);
    float h = 0.f;
    for (int c = 0; c < NCH; ++c) {
        size_t o = hs_off(b, c, s, d);
        float he  = hstate[o];
        float Sdt = sdtbuf[((size_t)(b * NCH + c) << 9) + d];
        hstate[o] = h;
        h = __expf(A * Sdt) * h + he;
    }
}

__global__ __launch_bounds__(256) void scan_phase3(const float* __restrict__ dtz,
                                                   const unsigned short* __restrict__ xcb,
                                                   const float* __restrict__ xdbl,
                                                   const unsigned short* __restrict__ xzb,
                                                   const float* __restrict__ hstate,
                                                   const float* __restrict__ A_log,
                                                   const float* __restrict__ Dp,
                                                   unsigned short* __restrict__ yb)
{
    int half = blockIdx.x & 1;
    int c    = (blockIdx.x >> 1) & (NCH - 1);
    int b    = blockIdx.x >> 8;
    int d    = (half << 8) + threadIdx.x;
    int row0 = b * LLEN + c * CLEN;

    __shared__ float bc[CLEN][32];   // [t][0:16]=B, [t][16:32]=C
    {
        int r = threadIdx.x >> 4, col = (threadIdx.x & 15) << 1;
        const float* src = xdbl + (size_t)(row0 + r) * NXDc + DTRc + col;
        bc[r][col] = src[0]; bc[r][col + 1] = src[1];
    }

    float A[DSc];
#pragma unroll
    for (int s = 0; s < DSc; ++s) A[s] = -__expf(A_log[d * DSc + s]);
    float Dv = Dp[d];

    float dtv[CLEN], xcv[CLEN], zv[CLEN];
#pragma unroll
    for (int t = 0; t < CLEN; ++t) {
        dtv[t] = dtz[((size_t)(row0 + t) << 9) + d];
        xcv[t] = bf2f(xcb[((size_t)(row0 + t) << 9) + d]);
        zv[t]  = bf2f(xzb[((size_t)(row0 + t) << 10) + DIc + d]);
    }

    float h[DSc];
#pragma unroll
    for (int s = 0; s < DSc; ++s) h[s] = hstate[hs_off(b, c, s, d)];  // h_in
    __syncthreads();

#pragma unroll
    for (int t = 0; t < CLEN; ++t) {
        float dBx = dtv[t] * xcv[t];
        float acc = 0.f;
#pragma unroll
        for (int s = 0; s < DSc; ++s) {
            float dA = __expf(dtv[t] * A[s]);
            h[s] = dA * h[s] + dBx * bc[t][s];
            acc += h[s] * bc[t][DSc + s];
        }
        float yv = (acc + xcv[t] * Dv) * (zv[t] * sigmoidf_(zv[t]));
        yb[((size_t)(row0 + t) << 9) + d] = f2bf(yv);
    }
}

// ---------------------------------------------------------------------------
extern "C" void kernel_launch(void* const* d_in, const int* in_sizes, int n_in,
                              void* d_out, int out_size, void* d_ws, size_t ws_size,
                              hipStream_t stream)
{
    const float* x      = (const float*)d_in[0];
    const float* W_in   = (const float*)d_in[1];
    const float* conv_w = (const float*)d_in[2];
    const float* conv_b = (const float*)d_in[3];
    const float* W_xp   = (const float*)d_in[4];
    const float* W_dt   = (const float*)d_in[5];
    const float* b_dt   = (const float*)d_in[6];
    const float* A_log  = (const float*)d_in[7];
    const float* D_par  = (const float*)d_in[8];
    const float* W_out  = (const float*)d_in[9];
    float* out = (float*)d_out;

    // workspace layout (all sizes in bytes, ~72 MB total)
    unsigned short* xb   = (unsigned short*)d_ws;            // [8192,512]  bf16: x, then y
    unsigned short* xzb  = xb  + (size_t)BLT * DIc;          // [8192,1024] bf16: xz
    unsigned short* xcb  = xzb + (size_t)BLT * 1024;         // [8192,512]  bf16: xc
    unsigned short* Wb   = xcb + (size_t)BLT * DIc;          // [1024,512]  bf16
    unsigned short* Wob  = Wb  + (size_t)1024 * DMc;         // [512,512]   bf16
    float* xdbl   = (float*)(Wob + (size_t)DMc * DIc);       // [8192,64]   f32
    float* dtz    = xdbl + (size_t)BLT * NXDc;               // [8192,512]  f32
    float* hstate = dtz  + (size_t)BLT * DIc;                // [4,128,16,512] f32
    float* sdtbuf = hstate + (size_t)BBc * NCH * DSc * DIc;  // [4,128,512] f32

    // 0. f32 -> bf16 conversions (x, W_in, W_out)
    convert3_kernel<<<(CN1 + CN2 + CN3 + 255) / 256, 256, 0, stream>>>(
        x, W_in, W_out, xb, Wb, Wob);

    // 1. xz = x @ W_in^T (M=8192,N=1024,K=512), bf16 out, XCD-swizzled
    gemm_mfma<0, 1><<<dim3(1024 / 128, BLT / 128), 256, 0, stream>>>(
        xb, Wb, nullptr, xzb, 1024, DMc);

    // 2. depthwise causal conv + SiLU -> xcb (bf16, 8-wide)
    conv_silu_kernel<<<(BLT * DIc / 8) / 256, 256, 0, stream>>>(xzb, conv_w, conv_b, xcb);

    // 3. x_dbl = xc @ W_xproj^T (M=8192,N=64,K=512), bf16 A
    gemm_xdbl<<<dim3(1, BLT / 64), 256, 0, stream>>>(xcb, W_xp, xdbl);

    // 4. dt = softplus(x_dbl[:, :32] @ W_dt^T + b_dt) -> dtz (f32)
    gemm_bt_f32<2><<<dim3(DIc / 64, BLT / 64), 256, 0, stream>>>(
        xdbl, W_dt, b_dt, dtz, BLT, DIc, DTRc, NXDc, DTRc, DIc);

    // 5. chunked parallel scan; y (bf16) into xb
    scan_phase1<<<BBc * NCH * 2, 256, 0, stream>>>(dtz, xcb, xdbl, A_log, hstate, sdtbuf);
    scan_phase2<<<(BBc * DSc * DIc) / 64, 64, 0, stream>>>(hstate, sdtbuf, A_log);
    scan_phase3<<<BBc * NCH * 2, 256, 0, stream>>>(dtz, xcb, xdbl, xzb, hstate,
                                                   A_log, D_par, xb);

    // 6. out = clip(y @ W_out^T) (M=8192,N=512,K=512), f32 out, XCD-swizzled
    gemm_mfma<1, 0><<<dim3(DMc / 128, BLT / 128), 256, 0, stream>>>(
        xb, Wob, out, nullptr, DMc, DMc);
}